// Round 6
// baseline (83.990 us; speedup 1.0000x reference)
//
#include <hip/hip_runtime.h>
#include <math.h>

#define MROWS 32768   // B*T
#define DDIM  1024
#define EDIM  64
#define NCH   64      // K-chunks of 16
#define TILEM 64      // rows per block

typedef _Float16 f16x8 __attribute__((ext_vector_type(8)));
typedef float    f32x16 __attribute__((ext_vector_type(16)));

// ws layout per chunk c (4096 halves = 8 KB), B-frag-linear (verified R4/R5):
//   half index = c*4096 + p*2048 + nf*512 + lane*8 + j
//   B frag (32x32x16): col = nf*32 + (lane&31), k = (lane>>5)*8 + j
//   nf: 0,1 = route cols 0-31,32-63 ; 2,3 = noise cols 0-31,32-63
__global__ __launch_bounds__(256)
void convW_kernel(const float* __restrict__ Wr, const float* __restrict__ Wn,
                  unsigned short* __restrict__ ws) {
    int gid = blockIdx.x * 256 + threadIdx.x;   // 131072 total
    int c32 = gid & 31;
    int j   = (gid >> 5) & 7;
    int lhi = (gid >> 8) & 1;
    int nf  = (gid >> 9) & 3;
    int c   = gid >> 11;
    int lane = lhi * 32 + c32;
    int k   = c * 16 + lhi * 8 + j;
    int col = nf * 32 + c32;
    float w = (col < EDIM) ? Wr[k * EDIM + col] : Wn[k * EDIM + (col - EDIM)];
    _Float16 hi = (_Float16)w;
    _Float16 lo = (_Float16)((w - (float)hi) * 2048.0f);
    union { _Float16 h; unsigned short u; } cv;
    size_t base = (size_t)c * 4096 + nf * 512 + lane * 8 + j;
    cv.h = hi; ws[base]        = cv.u;
    cv.h = lo; ws[base + 2048] = cv.u;
}

__global__ __launch_bounds__(256)
void router_mfma(const float* __restrict__ X,
                 const unsigned short* __restrict__ WS,
                 const float* __restrict__ br_g,
                 const float* __restrict__ bn_g,
                 const float* __restrict__ U,
                 float* __restrict__ out)
{
    __shared__ float NZ[TILEM][66];   // noisy-logit exchange tile (epilogue only)

    const int t    = threadIdx.x;
    const int lane = t & 63;
    const int wid  = t >> 6;
    const int wm   = wid >> 1;    // row-group 0/1 (32 rows each)
    const int wn   = wid & 1;     // expert-half 0/1 (cols wn*32..wn*32+31)
    const int rowBase = blockIdx.x * TILEM;
    const int myRow = rowBase + wm * 32 + (lane & 31);
    const int kSub  = (lane >> 5) * 8;
    const float* xp = X + (size_t)myRow * DDIM + kSub;
    const unsigned short* bpR = WS + wn * 512 + lane * 8;         // route nf = wn
    const unsigned short* bpN = WS + (wn + 2) * 512 + lane * 8;   // noise nf = wn+2

    f32x16 aR0, aR1, aN0, aN1;
#pragma unroll
    for (int i = 0; i < 16; ++i) { aR0[i] = 0.f; aR1[i] = 0.f; aN0[i] = 0.f; aN1[i] = 0.f; }

    auto convA8 = [&](const float4& a, const float4& b, f16x8& hi, f16x8& lo) {
        float x[8] = {a.x, a.y, a.z, a.w, b.x, b.y, b.z, b.w};
#pragma unroll
        for (int j = 0; j < 8; ++j) {
            _Float16 h = (_Float16)x[j];
            hi[j] = h;
            lo[j] = (_Float16)((x[j] - (float)h) * 2048.0f);
        }
    };

    auto step = [&](int c, const float4& x0, const float4& x1) {
        const unsigned short* cR = bpR + (size_t)c * 4096;
        const unsigned short* cN = bpN + (size_t)c * 4096;
        f16x8 bhiR = *(const f16x8*)(cR);
        f16x8 bloR = *(const f16x8*)(cR + 2048);
        f16x8 bhiN = *(const f16x8*)(cN);
        f16x8 bloN = *(const f16x8*)(cN + 2048);
        f16x8 ahi, alo;
        convA8(x0, x1, ahi, alo);
        aR0 = __builtin_amdgcn_mfma_f32_32x32x16_f16(ahi, bhiR, aR0, 0, 0, 0);
        aR1 = __builtin_amdgcn_mfma_f32_32x32x16_f16(ahi, bloR, aR1, 0, 0, 0);
        aR1 = __builtin_amdgcn_mfma_f32_32x32x16_f16(alo, bhiR, aR1, 0, 0, 0);
        aN0 = __builtin_amdgcn_mfma_f32_32x32x16_f16(ahi, bhiN, aN0, 0, 0, 0);
        aN1 = __builtin_amdgcn_mfma_f32_32x32x16_f16(ahi, bloN, aN1, 0, 0, 0);
        aN1 = __builtin_amdgcn_mfma_f32_32x32x16_f16(alo, bhiN, aN1, 0, 0, 0);
    };

    // X prefetch, depth 2 chunks (xA = even, xB = odd)
    float4 xA0 = *(const float4*)(xp);
    float4 xA1 = *(const float4*)(xp + 4);
    float4 xB0 = *(const float4*)(xp + 16);
    float4 xB1 = *(const float4*)(xp + 20);

    for (int c = 0; c < NCH; c += 2) {
        float4 nA0, nA1, nB0, nB1;
        if (c + 2 < NCH) {
            nA0 = *(const float4*)(xp + (c + 2) * 16);
            nA1 = *(const float4*)(xp + (c + 2) * 16 + 4);
            nB0 = *(const float4*)(xp + (c + 3) * 16);
            nB1 = *(const float4*)(xp + (c + 3) * 16 + 4);
        }
        step(c,     xA0, xA1);
        step(c + 1, xB0, xB1);
        xA0 = nA0; xA1 = nA1; xB0 = nB0; xB1 = nB1;
    }

    // ---- epilogue: combine, noisy into LDS, butterfly top-2 ----
    const int c0  = lane & 31;
    const int eCol = wn * 32 + c0;
    const float brv = br_g[eCol];
    const float bnv = bn_g[eCol];
    const float inv2048 = 1.0f / 2048.0f;
#pragma unroll
    for (int reg = 0; reg < 16; ++reg) {
        int lrow = wm * 32 + (reg & 3) + 8 * (reg >> 2) + 4 * (lane >> 5);
        int grow = rowBase + lrow;
        float vR = aR0[reg] + aR1[reg] * inv2048;
        float vN = aN0[reg] + aN1[reg] * inv2048;
        float u  = U[(size_t)grow * EDIM + eCol];
        NZ[lrow][eCol] = (vR + brv) + u * log1pf(expf(vN + bnv));
    }
    __syncthreads();

#pragma unroll 4
    for (int r = 0; r < 16; ++r) {
        int lrow = wid * 16 + r;
        int grow = rowBase + lrow;
        float noisy = NZ[lrow][lane];

        float m1 = noisy; int i1 = lane;
        float m2 = -INFINITY; int i2 = 64;
#pragma unroll
        for (int s = 1; s < 64; s <<= 1) {
            float om1 = __shfl_xor(m1, s); int oi1 = __shfl_xor(i1, s);
            float om2 = __shfl_xor(m2, s); int oi2 = __shfl_xor(i2, s);
            bool aw = (m1 > om1) || (m1 == om1 && i1 < oi1);
            float w1  = aw ? m1 : om1;  int wi1  = aw ? i1 : oi1;
            float c2a = aw ? m2 : om2;  int c2ai = aw ? i2 : oi2;
            float c2b = aw ? om1 : m1;  int c2bi = aw ? oi1 : i1;
            bool bw = (c2b > c2a) || (c2b == c2a && c2bi < c2ai);
            m1 = w1; i1 = wi1;
            m2 = bw ? c2b : c2a;
            i2 = bw ? c2bi : c2ai;
        }
        float e2  = expf(m2 - m1);
        float inv = 1.0f / (1.0f + e2);
        float p   = (lane == i1) ? inv : ((lane == i2) ? e2 * inv : 0.0f);
        out[(size_t)grow * EDIM + lane] = p;
        if (lane < 2)
            out[(size_t)MROWS * EDIM + (size_t)grow * 2 + lane] =
                (float)(lane == 0 ? i1 : i2);
    }
}

extern "C" void kernel_launch(void* const* d_in, const int* in_sizes, int n_in,
                              void* d_out, int out_size, void* d_ws, size_t ws_size,
                              hipStream_t stream) {
    const float* X  = (const float*)d_in[0];  // mh_output [8,4096,1024]
    const float* Wr = (const float*)d_in[1];  // W_route   [1024,64]
    const float* br = (const float*)d_in[2];  // b_route   [64]
    const float* Wn = (const float*)d_in[3];  // W_noise   [1024,64]
    const float* bn = (const float*)d_in[4];  // b_noise   [64]
    const float* U  = (const float*)d_in[5];  // noise_u   [8,4096,64]
    (void)in_sizes; (void)n_in; (void)ws_size; // uses 512 KB of d_ws
    unsigned short* ws16 = (unsigned short*)d_ws;
    convW_kernel<<<512, 256, 0, stream>>>(Wr, Wn, ws16);
    router_mfma<<<MROWS / TILEM, 256, 0, stream>>>(X, ws16, br, bn, U, (float*)d_out);
}

// Round 7
// 75.788 us; speedup vs baseline: 1.1082x; 1.1082x over previous
//
#include <hip/hip_runtime.h>
#include <math.h>

#define MROWS 32768   // B*T
#define DDIM  1024
#define EDIM  64
#define TILEM 64      // rows per block
#define NBIG  16      // big K-steps of 64
// WS: 64 chunks of 16-k, each 4096 halves (8 KB), frag-linear (verified R4-R6)

typedef _Float16 f16x8 __attribute__((ext_vector_type(8)));
typedef float    f32x16 __attribute__((ext_vector_type(16)));

__global__ __launch_bounds__(256)
void convW_kernel(const float* __restrict__ Wr, const float* __restrict__ Wn,
                  unsigned short* __restrict__ ws) {
    int gid = blockIdx.x * 256 + threadIdx.x;   // 131072 total
    int c32 = gid & 31;
    int j   = (gid >> 5) & 7;
    int lhi = (gid >> 8) & 1;
    int nf  = (gid >> 9) & 3;
    int c   = gid >> 11;
    int lane = lhi * 32 + c32;
    int k   = c * 16 + lhi * 8 + j;
    int col = nf * 32 + c32;                    // 0..63 route, 64..127 noise
    float w = (col < EDIM) ? Wr[k * EDIM + col] : Wn[k * EDIM + (col - EDIM)];
    _Float16 hi = (_Float16)w;
    _Float16 lo = (_Float16)((w - (float)hi) * 2048.0f);
    union { _Float16 h; unsigned short u; } cv;
    size_t base = (size_t)c * 4096 + nf * 512 + lane * 8 + j;
    cv.h = hi; ws[base]        = cv.u;
    cv.h = lo; ws[base + 2048] = cv.u;
}

__global__ __launch_bounds__(256)
void router_mfma(const float* __restrict__ X,
                 const unsigned short* __restrict__ WS,
                 const float* __restrict__ br_g,
                 const float* __restrict__ bn_g,
                 const float* __restrict__ U,
                 float* __restrict__ out)
{
    // B double buffer 2x32 KB; epilogue reuses as NZ[64][66] f32
    __shared__ alignas(16) unsigned char smem[65536];

    const int t    = threadIdx.x;
    const int lane = t & 63;
    const int wid  = t >> 6;
    const int wm   = wid >> 1;    // row-group 0/1
    const int wn   = wid & 1;     // col-half 0/1 (route nf=wn, noise nf=wn+2)
    const int rowBase = blockIdx.x * TILEM;
    const int myRow = rowBase + wm * 32 + (lane & 31);
    const int kSub  = (lane >> 5) * 8;
    const float* xp = X + (size_t)myRow * DDIM + kSub;
    const char* wsB = (const char*)WS;

    f32x16 aR0, aR1, aN0, aN1;
#pragma unroll
    for (int i = 0; i < 16; ++i) { aR0[i] = 0.f; aR1[i] = 0.f; aN0[i] = 0.f; aN1[i] = 0.f; }

    // stage one big step (4 k16-chunks = 32 KB) into buf: linear DMA
    auto stage = [&](int kb, int buf) {
#pragma unroll
        for (int r = 0; r < 8; ++r) {
            int o = buf * 32768 + wid * 8192 + r * 1024 + lane * 16;
            __builtin_amdgcn_global_load_lds(
                (const __attribute__((address_space(1))) void*)(wsB + (size_t)kb * 32768 + wid * 8192 + r * 1024 + lane * 16),
                (__attribute__((address_space(3))) void*)((char*)smem + o),
                16, 0, 0);
        }
    };

    auto convA8 = [&](const float4& a, const float4& b, f16x8& hi, f16x8& lo) {
        float x[8] = {a.x, a.y, a.z, a.w, b.x, b.y, b.z, b.w};
#pragma unroll
        for (int j = 0; j < 8; ++j) {
            _Float16 h = (_Float16)x[j];
            hi[j] = h;
            lo[j] = (_Float16)((x[j] - (float)h) * 2048.0f);
        }
    };

    // compute one big step from buf using X regs xr[4][2]
    auto computeBig = [&](int buf, float4 (*xr)[2]) {
        const unsigned short* Bb = (const unsigned short*)(smem + buf * 32768);
#pragma unroll
        for (int s = 0; s < 4; ++s) {
            const unsigned short* cR = Bb + s * 4096 + wn * 512 + lane * 8;
            const unsigned short* cN = Bb + s * 4096 + (wn + 2) * 512 + lane * 8;
            f16x8 bhiR = *(const f16x8*)(cR);
            f16x8 bloR = *(const f16x8*)(cR + 2048);
            f16x8 bhiN = *(const f16x8*)(cN);
            f16x8 bloN = *(const f16x8*)(cN + 2048);
            f16x8 ahi, alo;
            convA8(xr[s][0], xr[s][1], ahi, alo);
            aR0 = __builtin_amdgcn_mfma_f32_32x32x16_f16(ahi, bhiR, aR0, 0, 0, 0);
            aR1 = __builtin_amdgcn_mfma_f32_32x32x16_f16(ahi, bloR, aR1, 0, 0, 0);
            aR1 = __builtin_amdgcn_mfma_f32_32x32x16_f16(alo, bhiR, aR1, 0, 0, 0);
            aN0 = __builtin_amdgcn_mfma_f32_32x32x16_f16(ahi, bhiN, aN0, 0, 0, 0);
            aN1 = __builtin_amdgcn_mfma_f32_32x32x16_f16(ahi, bloN, aN1, 0, 0, 0);
            aN1 = __builtin_amdgcn_mfma_f32_32x32x16_f16(alo, bhiN, aN1, 0, 0, 0);
        }
    };

    auto loadX = [&](int kb, float4 (*xr)[2]) {
#pragma unroll
        for (int s = 0; s < 4; ++s) {
            xr[s][0] = *(const float4*)(xp + (kb * 4 + s) * 16);
            xr[s][1] = *(const float4*)(xp + (kb * 4 + s) * 16 + 4);
        }
    };

    float4 XA[4][2], XB[4][2];

    // ---- prologue ----
    stage(0, 0);
    loadX(0, XA);
    __syncthreads();

#pragma unroll 2
    for (int kb = 0; kb < NBIG; ++kb) {
        const int buf = kb & 1;
        float4 (*cur)[2] = (kb & 1) ? XB : XA;
        float4 (*nxt)[2] = (kb & 1) ? XA : XB;
        if (kb + 1 < NBIG) {
            stage(kb + 1, buf ^ 1);
            loadX(kb + 1, nxt);
        }
        computeBig(buf, cur);
        __syncthreads();
    }

    // ---- epilogue: combine hi/lo, noisy into LDS, butterfly top-2 ----
    float* NZp = (float*)smem;   // NZ[64][66]
    const int c0   = lane & 31;
    const int eCol = wn * 32 + c0;
    const float brv = br_g[eCol];
    const float bnv = bn_g[eCol];
    const float inv2048 = 1.0f / 2048.0f;
#pragma unroll
    for (int reg = 0; reg < 16; ++reg) {
        int lrow = wm * 32 + (reg & 3) + 8 * (reg >> 2) + 4 * (lane >> 5);
        int grow = rowBase + lrow;
        float vR = aR0[reg] + aR1[reg] * inv2048;
        float vN = aN0[reg] + aN1[reg] * inv2048;
        float u  = U[(size_t)grow * EDIM + eCol];
        NZp[lrow * 66 + eCol] = (vR + brv) + u * log1pf(expf(vN + bnv));
    }
    __syncthreads();

#pragma unroll 4
    for (int r = 0; r < 16; ++r) {
        int lrow = wid * 16 + r;
        int grow = rowBase + lrow;
        float noisy = NZp[lrow * 66 + lane];

        float m1 = noisy; int i1 = lane;
        float m2 = -INFINITY; int i2 = 64;
#pragma unroll
        for (int s = 1; s < 64; s <<= 1) {
            float om1 = __shfl_xor(m1, s); int oi1 = __shfl_xor(i1, s);
            float om2 = __shfl_xor(m2, s); int oi2 = __shfl_xor(i2, s);
            bool aw = (m1 > om1) || (m1 == om1 && i1 < oi1);
            float w1  = aw ? m1 : om1;  int wi1  = aw ? i1 : oi1;
            float c2a = aw ? m2 : om2;  int c2ai = aw ? i2 : oi2;
            float c2b = aw ? om1 : m1;  int c2bi = aw ? oi1 : i1;
            bool bw = (c2b > c2a) || (c2b == c2a && c2bi < c2ai);
            m1 = w1; i1 = wi1;
            m2 = bw ? c2b : c2a;
            i2 = bw ? c2bi : c2ai;
        }
        float e2  = expf(m2 - m1);
        float inv = 1.0f / (1.0f + e2);
        float p   = (lane == i1) ? inv : ((lane == i2) ? e2 * inv : 0.0f);
        out[(size_t)grow * EDIM + lane] = p;
        if (lane < 2)
            out[(size_t)MROWS * EDIM + (size_t)grow * 2 + lane] =
                (float)(lane == 0 ? i1 : i2);
    }
}

extern "C" void kernel_launch(void* const* d_in, const int* in_sizes, int n_in,
                              void* d_out, int out_size, void* d_ws, size_t ws_size,
                              hipStream_t stream) {
    const float* X  = (const float*)d_in[0];  // mh_output [8,4096,1024]
    const float* Wr = (const float*)d_in[1];  // W_route   [1024,64]
    const float* br = (const float*)d_in[2];  // b_route   [64]
    const float* Wn = (const float*)d_in[3];  // W_noise   [1024,64]
    const float* bn = (const float*)d_in[4];  // b_noise   [64]
    const float* U  = (const float*)d_in[5];  // noise_u   [8,4096,64]
    (void)in_sizes; (void)n_in; (void)ws_size; // uses 512 KB of d_ws
    unsigned short* ws16 = (unsigned short*)d_ws;
    convW_kernel<<<512, 256, 0, stream>>>(Wr, Wn, ws16);
    router_mfma<<<MROWS / TILEM, 256, 0, stream>>>(X, ws16, br, bn, U, (float*)d_out);
}